// Round 1
// baseline (34.150 us; speedup 1.0000x reference)
//
#include <hip/hip_runtime.h>

static constexpr int NPIX = 256 * 256;

// Monotone float<->uint mapping so atomicMax/atomicMin on uint == float max/min.
__device__ __forceinline__ unsigned int f2key(float f) {
    unsigned int u = __float_as_uint(f);
    return (u & 0x80000000u) ? ~u : (u | 0x80000000u);
}
__device__ __forceinline__ float key2f(unsigned int k) {
    unsigned int u = (k & 0x80000000u) ? (k ^ 0x80000000u) : ~k;
    return __uint_as_float(u);
}

__global__ void init_keys(unsigned int* keys) {
    // keys[0]=max(v2), keys[1]=min(v6), keys[2]=max(v8), keys[3]=min(v21)
    keys[0] = 0u;           // identity for max in key-space
    keys[1] = 0xFFFFFFFFu;  // identity for min in key-space
    keys[2] = 0u;
    keys[3] = 0xFFFFFFFFu;
}

// One thread per (h,w) pixel. Computes v2 for all (b=0..5, c=0..2), tracks
// per-channel batch max -> M[3][256][256], and block-reduces the 4 global
// scalars into atomic keys.
__global__ __launch_bounds__(256) void k_compute(const float* __restrict__ x,
                                                 const float* __restrict__ Wp,
                                                 const float* __restrict__ bp,
                                                 float* __restrict__ M,
                                                 unsigned int* __restrict__ keys) {
    const int p = blockIdx.x * 256 + threadIdx.x;  // pixel index, 0..65535

    float W[9];
#pragma unroll
    for (int i = 0; i < 9; ++i) W[i] = Wp[i];  // W[i*3+o], torch (in,out) layout
    const float b0 = bp[0], b1 = bp[1], b2 = bp[2];
    const float bias[3] = {b0, b1, b2};

    float maxv2 = -3.4e38f, minv6 = 3.4e38f, maxv8 = -3.4e38f, minv21 = 3.4e38f;
    float Mc[3] = {-3.4e38f, -3.4e38f, -3.4e38f};

    for (int b = 0; b < 6; ++b) {
        const float x0 = x[(b * 3 + 0) * NPIX + p];
        const float x1 = x[(b * 3 + 1) * NPIX + p];
        const float x2 = x[(b * 3 + 2) * NPIX + p];
#pragma unroll
        for (int c = 0; c < 3; ++c) {
            // v2 = einsum + bias + 3
            float v2 = fmaf(x0, W[c], fmaf(x1, W[3 + c], fmaf(x2, W[6 + c], bias[c] + 3.0f)));
            Mc[c] = fmaxf(Mc[c], v2);
            maxv2 = fmaxf(maxv2, v2);
            // v6 = relu(relu(3*v2)+3)
            float v6 = fmaxf(fmaxf(3.0f * v2, 0.0f) + 3.0f, 0.0f);
            minv6 = fminf(minv6, v6);
            float v7 = 3.0f * v6;
            maxv8 = fmaxf(maxv8, v7 + 3.0f);  // v8 = v7+3
            // v21 = relu(relu(relu(v7-3)-3)-3) - 3 - 3
            float t = fmaxf(v7 - 3.0f, 0.0f);
            t = fmaxf(t - 3.0f, 0.0f);
            t = fmaxf(t - 3.0f, 0.0f);
            minv21 = fminf(minv21, t - 6.0f);
        }
    }

    M[0 * NPIX + p] = Mc[0];
    M[1 * NPIX + p] = Mc[1];
    M[2 * NPIX + p] = Mc[2];

    // wave (64-lane) reduce
#pragma unroll
    for (int o = 32; o > 0; o >>= 1) {
        maxv2 = fmaxf(maxv2, __shfl_down(maxv2, o));
        minv6 = fminf(minv6, __shfl_down(minv6, o));
        maxv8 = fmaxf(maxv8, __shfl_down(maxv8, o));
        minv21 = fminf(minv21, __shfl_down(minv21, o));
    }
    __shared__ float s0[4], s1[4], s2[4], s3[4];
    const int lane = threadIdx.x & 63, wid = threadIdx.x >> 6;
    if (lane == 0) { s0[wid] = maxv2; s1[wid] = minv6; s2[wid] = maxv8; s3[wid] = minv21; }
    __syncthreads();
    if (threadIdx.x == 0) {
        float a = fmaxf(fmaxf(s0[0], s0[1]), fmaxf(s0[2], s0[3]));
        float bmn = fminf(fminf(s1[0], s1[1]), fminf(s1[2], s1[3]));
        float c = fmaxf(fmaxf(s2[0], s2[1]), fmaxf(s2[2], s2[3]));
        float d = fminf(fminf(s3[0], s3[1]), fminf(s3[2], s3[3]));
        atomicMax(&keys[0], f2key(a));
        atomicMin(&keys[1], f2key(bmn));
        atomicMax(&keys[2], f2key(c));
        atomicMin(&keys[3], f2key(d));
    }
}

__global__ void k_scalar(const unsigned int* __restrict__ keys, float* __restrict__ S) {
    // out = m1 + max(v46) + min(v47) + max(v8) + min(v21) + min(v33)
    //     = m1 + max(v2) + 2*min(v6) + max(v8) + min(v21)
    *S = key2f(keys[0]) + 2.0f * key2f(keys[1]) + key2f(keys[2]) + key2f(keys[3]);
}

// out[x,k,w] = M[k%3, x%256, w%256] + S ; float4-vectorized.
__global__ __launch_bounds__(256) void k_out(const float* __restrict__ M,
                                             const float* __restrict__ Sp,
                                             float4* __restrict__ out) {
    const float S = *Sp;
    const int i = blockIdx.x * 256 + threadIdx.x;  // 1,327,104 threads
    const int base = i * 4;
    const int w = base % 768;
    const int t = base / 768;
    const int k = t % 9;
    const int xr = t / 9;
    const int c = (k >= 6) ? (k - 6) : ((k >= 3) ? (k - 3) : k);
    const float4 m = *reinterpret_cast<const float4*>(&M[c * NPIX + (xr & 255) * 256 + (w & 255)]);
    out[i] = make_float4(m.x + S, m.y + S, m.z + S, m.w + S);
}

extern "C" void kernel_launch(void* const* d_in, const int* in_sizes, int n_in,
                              void* d_out, int out_size, void* d_ws, size_t ws_size,
                              hipStream_t stream) {
    const float* x = (const float*)d_in[0];   // [6,3,256,256]
    const float* W = (const float*)d_in[1];   // [3,3] (in,out)
    const float* b = (const float*)d_in[2];   // [3]
    float* out = (float*)d_out;               // [768,9,768]

    float* M = (float*)d_ws;                                          // 3*65536 floats
    unsigned int* keys = (unsigned int*)((char*)d_ws + 3 * NPIX * 4); // 4 uints
    float* S = (float*)(keys + 4);                                    // 1 float

    hipLaunchKernelGGL(init_keys, dim3(1), dim3(1), 0, stream, keys);
    hipLaunchKernelGGL(k_compute, dim3(NPIX / 256), dim3(256), 0, stream, x, W, b, M, keys);
    hipLaunchKernelGGL(k_scalar, dim3(1), dim3(1), 0, stream, keys, S);
    hipLaunchKernelGGL(k_out, dim3((out_size / 4) / 256), dim3(256), 0, stream, M, S, (float4*)out);
}

// Round 2
// 29.580 us; speedup vs baseline: 1.1545x; 1.1545x over previous
//
#include <hip/hip_runtime.h>

static constexpr int NPIX = 256 * 256;

typedef float f4 __attribute__((ext_vector_type(4)));

// Monotone float<->uint mapping so atomicMax on uint == float max.
// Identity for max in key-space is 0 (all finite floats map to keys >= 0x00800000),
// so a 16-byte memset(0) initializes all four reductions.
__device__ __forceinline__ unsigned int f2key(float f) {
    unsigned int u = __float_as_uint(f);
    return (u & 0x80000000u) ? ~u : (u | 0x80000000u);
}
__device__ __forceinline__ float key2f(unsigned int k) {
    unsigned int u = (k & 0x80000000u) ? (k ^ 0x80000000u) : ~k;
    return __uint_as_float(u);
}

// One thread per (h,w) pixel. Computes v2 for all (b=0..5, c=0..2), tracks
// per-channel batch max -> M[3][256][256], and block-reduces 4 global scalars
// (all as MAX via negation trick) into atomic keys.
// keys[0]=max(v2), keys[1]=max(-v6), keys[2]=max(v8), keys[3]=max(-v21)
__global__ __launch_bounds__(256) void k_compute(const float* __restrict__ x,
                                                 const float* __restrict__ Wp,
                                                 const float* __restrict__ bp,
                                                 float* __restrict__ M,
                                                 unsigned int* __restrict__ keys) {
    const int p = blockIdx.x * 256 + threadIdx.x;  // pixel index, 0..65535

    float W[9];
#pragma unroll
    for (int i = 0; i < 9; ++i) W[i] = Wp[i];  // W[i*3+o], torch (in,out) layout
    const float bias[3] = {bp[0], bp[1], bp[2]};

    float maxv2 = -3.4e38f, maxnv6 = -3.4e38f, maxv8 = -3.4e38f, maxnv21 = -3.4e38f;
    float Mc[3] = {-3.4e38f, -3.4e38f, -3.4e38f};

#pragma unroll
    for (int b = 0; b < 6; ++b) {
        const float x0 = x[(b * 3 + 0) * NPIX + p];
        const float x1 = x[(b * 3 + 1) * NPIX + p];
        const float x2 = x[(b * 3 + 2) * NPIX + p];
#pragma unroll
        for (int c = 0; c < 3; ++c) {
            // v2 = einsum + bias + 3
            float v2 = fmaf(x0, W[c], fmaf(x1, W[3 + c], fmaf(x2, W[6 + c], bias[c] + 3.0f)));
            Mc[c] = fmaxf(Mc[c], v2);
            maxv2 = fmaxf(maxv2, v2);
            // v6 = relu(relu(3*v2)+3)
            float v6 = fmaxf(fmaxf(3.0f * v2, 0.0f) + 3.0f, 0.0f);
            maxnv6 = fmaxf(maxnv6, -v6);
            float v7 = 3.0f * v6;
            maxv8 = fmaxf(maxv8, v7 + 3.0f);  // v8 = v7+3
            // v21 = relu(relu(relu(v7-3)-3)-3) - 6
            float t = fmaxf(v7 - 3.0f, 0.0f);
            t = fmaxf(t - 3.0f, 0.0f);
            t = fmaxf(t - 3.0f, 0.0f);
            maxnv21 = fmaxf(maxnv21, -(t - 6.0f));
        }
    }

    M[0 * NPIX + p] = Mc[0];
    M[1 * NPIX + p] = Mc[1];
    M[2 * NPIX + p] = Mc[2];

    // wave (64-lane) reduce
#pragma unroll
    for (int o = 32; o > 0; o >>= 1) {
        maxv2 = fmaxf(maxv2, __shfl_down(maxv2, o));
        maxnv6 = fmaxf(maxnv6, __shfl_down(maxnv6, o));
        maxv8 = fmaxf(maxv8, __shfl_down(maxv8, o));
        maxnv21 = fmaxf(maxnv21, __shfl_down(maxnv21, o));
    }
    __shared__ float s0[4], s1[4], s2[4], s3[4];
    const int lane = threadIdx.x & 63, wid = threadIdx.x >> 6;
    if (lane == 0) { s0[wid] = maxv2; s1[wid] = maxnv6; s2[wid] = maxv8; s3[wid] = maxnv21; }
    __syncthreads();
    if (threadIdx.x == 0) {
        atomicMax(&keys[0], f2key(fmaxf(fmaxf(s0[0], s0[1]), fmaxf(s0[2], s0[3]))));
        atomicMax(&keys[1], f2key(fmaxf(fmaxf(s1[0], s1[1]), fmaxf(s1[2], s1[3]))));
        atomicMax(&keys[2], f2key(fmaxf(fmaxf(s2[0], s2[1]), fmaxf(s2[2], s2[3]))));
        atomicMax(&keys[3], f2key(fmaxf(fmaxf(s3[0], s3[1]), fmaxf(s3[2], s3[3]))));
    }
}

// out[x,k,w] = M[k%3, x%256, w%256] + S ; grid (9, 768) x 192 threads,
// one float4 per thread, no integer division, non-temporal stores.
__global__ __launch_bounds__(192) void k_out(const f4* __restrict__ Mv,
                                             const unsigned int* __restrict__ keys,
                                             f4* __restrict__ out) {
    // S = max(v2) + 2*min(v6) + max(v8) + min(v21)
    const float S = key2f(keys[0]) - 2.0f * key2f(keys[1]) + key2f(keys[2]) - key2f(keys[3]);

    const int k = blockIdx.x;   // 0..8
    const int xr = blockIdx.y;  // 0..767
    const int c = (k >= 6) ? (k - 6) : ((k >= 3) ? (k - 3) : k);

    const f4 m = Mv[c * (NPIX / 4) + (xr & 255) * 64 + (threadIdx.x & 63)];
    f4 r = m + S;
    __builtin_nontemporal_store(r, &out[(xr * 9 + k) * 192 + threadIdx.x]);
}

extern "C" void kernel_launch(void* const* d_in, const int* in_sizes, int n_in,
                              void* d_out, int out_size, void* d_ws, size_t ws_size,
                              hipStream_t stream) {
    const float* x = (const float*)d_in[0];   // [6,3,256,256]
    const float* W = (const float*)d_in[1];   // [3,3] (in,out)
    const float* b = (const float*)d_in[2];   // [3]

    float* M = (float*)d_ws;                                           // 3*65536 floats
    unsigned int* keys = (unsigned int*)((char*)d_ws + 3 * NPIX * 4);  // 4 uints

    hipMemsetAsync(keys, 0, 4 * sizeof(unsigned int), stream);
    hipLaunchKernelGGL(k_compute, dim3(NPIX / 256), dim3(256), 0, stream, x, W, b, M, keys);
    hipLaunchKernelGGL(k_out, dim3(9, 768), dim3(192), 0, stream, (const f4*)M, keys, (f4*)d_out);
}